// Round 3
// baseline (275.372 us; speedup 1.0000x reference)
//
#include <hip/hip_runtime.h>

// Problem constants (x: (512, 9, 84, 84) f32)
#define N_ELEM   7056        // 84*84
#define DIM      84
#define M_STEPS  14111       // 2*N_ELEM - 1
#define N_ROWS   4608        // 512*9
#define NCHUNK   384
#define KSTEPS   37          // 384*37 = 14208 >= 14111 (tail chunks empty -> identity)
#define WINW     208         // window: (K-1)+2*84+1 = 205, padded to 208
#define TPB      256
#define NJV      1764        // N_ELEM / 4

#define TRACE_BLOCKS 28      // 28 * 252 = 7056
#define GROUPS   16          // chunk groups for parallel partial maps
#define CPG      (NCHUNK / GROUPS)   // 24 chunks per group
#define ROWS_PB  2           // rows per gather block (2304 blocks -> sustains 5 blocks/CU)

typedef float fvec4 __attribute__((ext_vector_type(4)));  // native vec for NT stores

// ---- JAX threefry2x32 block cipher (20 rounds), bit-exact port ----
__device__ __forceinline__ void threefry2x32(unsigned k0, unsigned k1,
                                             unsigned x0, unsigned x1,
                                             unsigned &o0, unsigned &o1) {
  const unsigned ks0 = k0, ks1 = k1, ks2 = k0 ^ k1 ^ 0x1BD11BDAu;
  x0 += ks0; x1 += ks1;
#define ROTL(x, r) (((x) << (r)) | ((x) >> (32 - (r))))
#define RND(r) { x0 += x1; x1 = ROTL(x1, r); x1 ^= x0; }
  RND(13) RND(15) RND(26) RND(6)
  x0 += ks1; x1 += ks2 + 1u;
  RND(17) RND(29) RND(16) RND(24)
  x0 += ks2; x1 += ks0 + 2u;
  RND(13) RND(15) RND(26) RND(6)
  x0 += ks0; x1 += ks1 + 3u;
  RND(17) RND(29) RND(16) RND(24)
  x0 += ks1; x1 += ks2 + 4u;
  RND(13) RND(15) RND(26) RND(6)
  x0 += ks2; x1 += ks0 + 5u;
  o0 = x0; o1 = x1;
#undef RND
#undef ROTL
}

// jax.random.choice(key,5,p=[.55,.1125,.1125,.1125,.1125]) — searchsorted on f32
// cumsum (sequential f32 cumsum verified exact-arithmetic: q4 == 1.0f exactly).
__device__ __forceinline__ int r_from_bits(unsigned bits) {
  const float p8 = 0.1125f;
  const float q0 = 0.55f;
  const float q1 = q0 + p8;
  const float q2 = q1 + p8;
  const float q3 = q2 + p8;
  const float q4 = q3 + p8;
  float u  = __uint_as_float((bits >> 9) | 0x3F800000u) - 1.0f; // [0,1)
  float rv = q4 * (1.0f - u);
  return (int)(q0 < rv) + (int)(q1 < rv) + (int)(q2 < rv) + (int)(q3 < rv);
}

// Window bounds for chunk c: steps t in [t0,t1); touched positions are within
// [imin-DIM, imax+DIM] clamped to [0, N_ELEM-1], where i(t) = |t - (N_ELEM-1)|.
__device__ __forceinline__ void chunk_bounds(int c, int &t0, int &t1, int &lo, int &hi) {
  t0 = c * KSTEPS; if (t0 > M_STEPS) t0 = M_STEPS;
  t1 = t0 + KSTEPS; if (t1 > M_STEPS) t1 = M_STEPS;
  int a0 = t0 - (N_ELEM - 1);       if (a0 < 0) a0 = -a0;
  int a1 = (t1 - 1) - (N_ELEM - 1); if (a1 < 0) a1 = -a1;
  int imax = a0 > a1 ? a0 : a1;
  int imin;
  if (t0 <= N_ELEM - 1 && t1 - 1 >= N_ELEM - 1) imin = 0;
  else imin = a0 < a1 ? a0 : a1;
  lo = imin - DIM; if (lo < 0) lo = 0;
  hi = imax + DIM; if (hi > N_ELEM - 1) hi = N_ELEM - 1;
}

// Kernel 1 (merged chunk+trace): each block rebuilds its group's 24 chunk
// windows LOCALLY in LDS (lanes 0..23 run the 24 independent 37-step serial
// swap chains in parallel — identical logic to the verified chunk_kernel),
// then traces 252 indices through the group's chunks (c descending).
// Removes the winG global round-trip and one kernel launch.
__global__ __launch_bounds__(TPB) void permbuild_kernel(unsigned short* __restrict__ Pg) {
  __shared__ __align__(16) unsigned short w[CPG * WINW];   // 24*208*2 = 9984 B
  __shared__ unsigned char rs[CPG * KSTEPS];               // 888 B
  const int tid = threadIdx.x;
  const int g  = blockIdx.x / TRACE_BLOCKS;
  const int sb = blockIdx.x % TRACE_BLOCKS;

  // identity-init all 24 windows
  for (int idx = tid; idx < CPG * WINW; idx += TPB) {
    int c = idx / WINW;
    int j = idx - c * WINW;
    int t0, t1, lo, hi; chunk_bounds(g * CPG + c, t0, t1, lo, hi);
    w[idx] = (unsigned short)(lo + j);                     // pad entries unused
  }
  // all draws for the group's 24 chunks, computed in parallel
  for (int q = tid; q < CPG * KSTEPS; q += TPB) {
    int c = q / KSTEPS;
    int k = q - c * KSTEPS;
    int t = (g * CPG + c) * KSTEPS + k;
    unsigned y0, y1;
    threefry2x32(0u, 42u, 0u, (unsigned)t, y0, y1);
    rs[q] = (unsigned char)r_from_bits(y0 ^ y1);
  }
  __syncthreads();

  // 24 parallel serial swap chains (lane c owns chunk g*CPG+c)
  if (tid < CPG) {
    const int c = tid;
    int t0, t1, lo, hi; chunk_bounds(g * CPG + c, t0, t1, lo, hi);
    const int nt = t1 - t0;
    unsigned short* wc = &w[c * WINW];
    const unsigned char* rc = &rs[c * KSTEPS];
    for (int k = 0; k < nt; ++k) {
      int t = t0 + k;
      int i = t - (N_ELEM - 1); if (i < 0) i = -i;
      int r = rc[k];
      int off = (r == 1) ? 1 : (r == 2) ? -1 : (r == 3) ? DIM : (r == 4) ? -DIM : 0;
      int idx = i + off;
      bool doit = (r != 0) && (idx > 0) && (idx < N_ELEM);
      int je = doit ? idx : i;              // branchless self-swap when !doit
      unsigned short a = wc[i  - lo];
      unsigned short b = wc[je - lo];
      wc[i  - lo] = b;
      wc[je - lo] = a;
    }
  }
  __syncthreads();

  // trace 252 indices through chunks c = CPG-1 .. 0 of this group
  if (tid < 252) {
    int y = sb * 252 + tid;
    for (int c = CPG - 1; c >= 0; --c) {
      int t0, t1, lo, hi; chunk_bounds(g * CPG + c, t0, t1, lo, hi);
      unsigned e = (unsigned)(y - lo);
      if (e <= (unsigned)(hi - lo)) y = (int)w[c * WINW + e];
    }
    Pg[g * N_ELEM + sb * 252 + tid] = (unsigned short)y;
  }
}

// Kernel 2: compose the 16 partial maps: perm[j] = P_0[P_1[...P_15[j]]].
// (P_15 applied first = chunks 383..360, matching the original c=383..0 walk.)
__global__ __launch_bounds__(TPB) void compose_kernel(const unsigned short* __restrict__ Pg,
                                                      int* __restrict__ permG) {
  const int tid = threadIdx.x;
  if (tid >= 252) return;
  const int j = blockIdx.x * 252 + tid;
  int y = j;
#pragma unroll
  for (int g = GROUPS - 1; g >= 0; --g) y = (int)Pg[g * N_ELEM + y];
  permG[j] = y;
}

// Kernel 3: per-row LDS-staged gather, 2 rows per block.
// - perm held in registers (7 int4, loaded once per block)
// - next row prefetched into registers DURING the gather/store phase (T14)
// - output written with non-temporal stores (never re-read; keeps x in L3)
// __launch_bounds__(TPB, 5): 5 blocks/CU (LDS 28.2 KB each = 141 KB/CU).
__global__ __launch_bounds__(TPB, 5) void gather_kernel(const float* __restrict__ x,
                                                        const int* __restrict__ perm,
                                                        float* __restrict__ out) {
  __shared__ __align__(16) float row[N_ELEM];             // 28224 B
  const int tid = threadIdx.x;
  const int r0 = blockIdx.x * ROWS_PB;
  float4* row4 = (float4*)row;

  // perm fragment in registers (used for both rows)
  int4 p[7];
  const int4* p4 = (const int4*)perm;
#pragma unroll
  for (int k = 0; k < 7; ++k) {
    int v = tid + k * TPB;
    if (v < NJV) p[k] = p4[v];
  }

  // load row r0 into registers
  float4 buf[7];
  {
    const float4* xr4 = (const float4*)(x + (size_t)r0 * N_ELEM);
#pragma unroll
    for (int k = 0; k < 7; ++k) {
      int v = tid + k * TPB;
      if (v < NJV) buf[k] = xr4[v];
    }
  }

  for (int rr = 0; rr < ROWS_PB; ++rr) {
    // registers -> LDS (coalesced b128 writes)
#pragma unroll
    for (int k = 0; k < 7; ++k) {
      int v = tid + k * TPB;
      if (v < NJV) row4[v] = buf[k];
    }
    __syncthreads();

    // prefetch next row into registers; loads fly under the gather/store phase
    if (rr + 1 < ROWS_PB) {
      const float4* xn4 = (const float4*)(x + (size_t)(r0 + rr + 1) * N_ELEM);
#pragma unroll
      for (int k = 0; k < 7; ++k) {
        int v = tid + k * TPB;
        if (v < NJV) buf[k] = xn4[v];
      }
    }

    // gather from LDS, non-temporal coalesced store (native vec type for builtin)
    fvec4* or4 = (fvec4*)(out + (size_t)(r0 + rr) * N_ELEM);
#pragma unroll
    for (int k = 0; k < 7; ++k) {
      int v = tid + k * TPB;
      if (v < NJV) {
        int4 pp = p[k];
        fvec4 o;
        o.x = row[pp.x]; o.y = row[pp.y]; o.z = row[pp.z]; o.w = row[pp.w];
        __builtin_nontemporal_store(o, &or4[v]);
      }
    }
    __syncthreads();   // LDS reads done before next row's write
  }
}

extern "C" void kernel_launch(void* const* d_in, const int* in_sizes, int n_in,
                              void* d_out, int out_size, void* d_ws, size_t ws_size,
                              hipStream_t stream) {
  const float* x = (const float*)d_in[0];
  float* out = (float*)d_out;

  // ws layout: Pg 225792 B | perm 28224 B
  unsigned short* Pg = (unsigned short*)d_ws;
  int* perm = (int*)((char*)d_ws + (size_t)GROUPS * N_ELEM * 2);

  permbuild_kernel<<<GROUPS * TRACE_BLOCKS, TPB, 0, stream>>>(Pg);
  compose_kernel<<<TRACE_BLOCKS, TPB, 0, stream>>>(Pg, perm);
  gather_kernel<<<N_ROWS / ROWS_PB, TPB, 0, stream>>>(x, perm, out);
}

// Round 4
// 269.556 us; speedup vs baseline: 1.0216x; 1.0216x over previous
//
#include <hip/hip_runtime.h>

// Problem constants (x: (512, 9, 84, 84) f32)
#define N_ELEM   7056        // 84*84
#define DIM      84
#define M_STEPS  14111       // 2*N_ELEM - 1
#define N_ROWS   4608        // 512*9
#define NCHUNK   384
#define KSTEPS   37          // 384*37 = 14208 >= 14111 (tail chunks empty -> identity)
#define WINW     208         // window: (K-1)+2*84+1 = 205, padded to 208
#define TPB      256
#define NJV      1764        // N_ELEM / 4

#define TRACE_BLOCKS 28      // 28 * 252 = 7056
#define GROUPS   16          // chunk groups for parallel partial maps
#define CPG      (NCHUNK / GROUPS)   // 24 chunks per group

#define GTPB     512         // gather block size: 4 blocks/CU * 8 waves = 32 waves = 100% occ
#define ROWS_PB  2           // rows per gather block
#define GK       4           // ceil(NJV / GTPB)

// ---- JAX threefry2x32 block cipher (20 rounds), bit-exact port ----
__device__ __forceinline__ void threefry2x32(unsigned k0, unsigned k1,
                                             unsigned x0, unsigned x1,
                                             unsigned &o0, unsigned &o1) {
  const unsigned ks0 = k0, ks1 = k1, ks2 = k0 ^ k1 ^ 0x1BD11BDAu;
  x0 += ks0; x1 += ks1;
#define ROTL(x, r) (((x) << (r)) | ((x) >> (32 - (r))))
#define RND(r) { x0 += x1; x1 = ROTL(x1, r); x1 ^= x0; }
  RND(13) RND(15) RND(26) RND(6)
  x0 += ks1; x1 += ks2 + 1u;
  RND(17) RND(29) RND(16) RND(24)
  x0 += ks2; x1 += ks0 + 2u;
  RND(13) RND(15) RND(26) RND(6)
  x0 += ks0; x1 += ks1 + 3u;
  RND(17) RND(29) RND(16) RND(24)
  x0 += ks1; x1 += ks2 + 4u;
  RND(13) RND(15) RND(26) RND(6)
  x0 += ks2; x1 += ks0 + 5u;
  o0 = x0; o1 = x1;
#undef RND
#undef ROTL
}

// jax.random.choice(key,5,p=[.55,.1125,.1125,.1125,.1125]) — searchsorted on f32
// cumsum (sequential f32 cumsum verified exact-arithmetic: q4 == 1.0f exactly).
__device__ __forceinline__ int r_from_bits(unsigned bits) {
  const float p8 = 0.1125f;
  const float q0 = 0.55f;
  const float q1 = q0 + p8;
  const float q2 = q1 + p8;
  const float q3 = q2 + p8;
  const float q4 = q3 + p8;
  float u  = __uint_as_float((bits >> 9) | 0x3F800000u) - 1.0f; // [0,1)
  float rv = q4 * (1.0f - u);
  return (int)(q0 < rv) + (int)(q1 < rv) + (int)(q2 < rv) + (int)(q3 < rv);
}

// Window bounds for chunk c: steps t in [t0,t1); touched positions are within
// [imin-DIM, imax+DIM] clamped to [0, N_ELEM-1], where i(t) = |t - (N_ELEM-1)|.
__device__ __forceinline__ void chunk_bounds(int c, int &t0, int &t1, int &lo, int &hi) {
  t0 = c * KSTEPS; if (t0 > M_STEPS) t0 = M_STEPS;
  t1 = t0 + KSTEPS; if (t1 > M_STEPS) t1 = M_STEPS;
  int a0 = t0 - (N_ELEM - 1);       if (a0 < 0) a0 = -a0;
  int a1 = (t1 - 1) - (N_ELEM - 1); if (a1 < 0) a1 = -a1;
  int imax = a0 > a1 ? a0 : a1;
  int imin;
  if (t0 <= N_ELEM - 1 && t1 - 1 >= N_ELEM - 1) imin = 0;
  else imin = a0 < a1 ? a0 : a1;
  lo = imin - DIM; if (lo < 0) lo = 0;
  hi = imax + DIM; if (hi > N_ELEM - 1) hi = N_ELEM - 1;
}

// Kernel 1 (merged chunk+trace): each block rebuilds its group's 24 chunk
// windows LOCALLY in LDS (lanes 0..23 run the 24 independent 37-step serial
// swap chains in parallel), then traces 252 indices through the group's
// chunks (c descending). Output P_g[y] as ushort.
__global__ __launch_bounds__(TPB) void permbuild_kernel(unsigned short* __restrict__ Pg) {
  __shared__ __align__(16) unsigned short w[CPG * WINW];   // 24*208*2 = 9984 B
  __shared__ unsigned char rs[CPG * KSTEPS];               // 888 B
  const int tid = threadIdx.x;
  const int g  = blockIdx.x / TRACE_BLOCKS;
  const int sb = blockIdx.x % TRACE_BLOCKS;

  // identity-init all 24 windows
  for (int idx = tid; idx < CPG * WINW; idx += TPB) {
    int c = idx / WINW;
    int j = idx - c * WINW;
    int t0, t1, lo, hi; chunk_bounds(g * CPG + c, t0, t1, lo, hi);
    w[idx] = (unsigned short)(lo + j);                     // pad entries unused
  }
  // all draws for the group's 24 chunks, computed in parallel
  for (int q = tid; q < CPG * KSTEPS; q += TPB) {
    int c = q / KSTEPS;
    int k = q - c * KSTEPS;
    int t = (g * CPG + c) * KSTEPS + k;
    unsigned y0, y1;
    threefry2x32(0u, 42u, 0u, (unsigned)t, y0, y1);
    rs[q] = (unsigned char)r_from_bits(y0 ^ y1);
  }
  __syncthreads();

  // 24 parallel serial swap chains (lane c owns chunk g*CPG+c)
  if (tid < CPG) {
    const int c = tid;
    int t0, t1, lo, hi; chunk_bounds(g * CPG + c, t0, t1, lo, hi);
    const int nt = t1 - t0;
    unsigned short* wc = &w[c * WINW];
    const unsigned char* rc = &rs[c * KSTEPS];
    for (int k = 0; k < nt; ++k) {
      int t = t0 + k;
      int i = t - (N_ELEM - 1); if (i < 0) i = -i;
      int r = rc[k];
      int off = (r == 1) ? 1 : (r == 2) ? -1 : (r == 3) ? DIM : (r == 4) ? -DIM : 0;
      int idx = i + off;
      bool doit = (r != 0) && (idx > 0) && (idx < N_ELEM);
      int je = doit ? idx : i;              // branchless self-swap when !doit
      unsigned short a = wc[i  - lo];
      unsigned short b = wc[je - lo];
      wc[i  - lo] = b;
      wc[je - lo] = a;
    }
  }
  __syncthreads();

  // trace 252 indices through chunks c = CPG-1 .. 0 of this group
  if (tid < 252) {
    int y = sb * 252 + tid;
    for (int c = CPG - 1; c >= 0; --c) {
      int t0, t1, lo, hi; chunk_bounds(g * CPG + c, t0, t1, lo, hi);
      unsigned e = (unsigned)(y - lo);
      if (e <= (unsigned)(hi - lo)) y = (int)w[c * WINW + e];
    }
    Pg[g * N_ELEM + sb * 252 + tid] = (unsigned short)y;
  }
}

// Kernel 2: compose the 16 partial maps: perm[j] = P_0[P_1[...P_15[j]]].
// (P_15 applied first = chunks 383..360, matching the original c=383..0 walk.)
__global__ __launch_bounds__(TPB) void compose_kernel(const unsigned short* __restrict__ Pg,
                                                      int* __restrict__ permG) {
  const int tid = threadIdx.x;
  if (tid >= 252) return;
  const int j = blockIdx.x * 252 + tid;
  int y = j;
#pragma unroll
  for (int g = GROUPS - 1; g >= 0; --g) y = (int)Pg[g * N_ELEM + y];
  permG[j] = y;
}

// Kernel 3: per-row LDS-staged gather, 2 rows per block, TPB=512.
// 28 KB LDS * 4 blocks/CU = 114 KB, 4 blocks * 8 waves = 32 waves/CU (100% occ).
// - perm held in registers (4 int4, loaded once per block)
// - next row prefetched into registers DURING the gather/store phase (T14)
// - plain stores (NT stores measured 2x write+fetch amplification — reverted)
__global__ __launch_bounds__(GTPB, 8) void gather_kernel(const float* __restrict__ x,
                                                         const int* __restrict__ perm,
                                                         float* __restrict__ out) {
  __shared__ __align__(16) float row[N_ELEM];             // 28224 B
  const int tid = threadIdx.x;
  const int r0 = blockIdx.x * ROWS_PB;
  float4* row4 = (float4*)row;

  // perm fragment in registers (used for both rows)
  int4 p[GK];
  const int4* p4 = (const int4*)perm;
#pragma unroll
  for (int k = 0; k < GK; ++k) {
    int v = tid + k * GTPB;
    if (v < NJV) p[k] = p4[v];
  }

  // load row r0 into registers
  float4 buf[GK];
  {
    const float4* xr4 = (const float4*)(x + (size_t)r0 * N_ELEM);
#pragma unroll
    for (int k = 0; k < GK; ++k) {
      int v = tid + k * GTPB;
      if (v < NJV) buf[k] = xr4[v];
    }
  }

  for (int rr = 0; rr < ROWS_PB; ++rr) {
    // registers -> LDS (coalesced b128 writes)
#pragma unroll
    for (int k = 0; k < GK; ++k) {
      int v = tid + k * GTPB;
      if (v < NJV) row4[v] = buf[k];
    }
    __syncthreads();

    // prefetch next row into registers; loads fly under the gather/store phase
    if (rr + 1 < ROWS_PB) {
      const float4* xn4 = (const float4*)(x + (size_t)(r0 + rr + 1) * N_ELEM);
#pragma unroll
      for (int k = 0; k < GK; ++k) {
        int v = tid + k * GTPB;
        if (v < NJV) buf[k] = xn4[v];
      }
    }

    // gather from LDS, coalesced store
    float4* or4 = (float4*)(out + (size_t)(r0 + rr) * N_ELEM);
#pragma unroll
    for (int k = 0; k < GK; ++k) {
      int v = tid + k * GTPB;
      if (v < NJV) {
        int4 pp = p[k];
        float4 o;
        o.x = row[pp.x]; o.y = row[pp.y]; o.z = row[pp.z]; o.w = row[pp.w];
        or4[v] = o;
      }
    }
    __syncthreads();   // LDS reads done before next row's write
  }
}

extern "C" void kernel_launch(void* const* d_in, const int* in_sizes, int n_in,
                              void* d_out, int out_size, void* d_ws, size_t ws_size,
                              hipStream_t stream) {
  const float* x = (const float*)d_in[0];
  float* out = (float*)d_out;

  // ws layout: Pg 225792 B | perm 28224 B
  unsigned short* Pg = (unsigned short*)d_ws;
  int* perm = (int*)((char*)d_ws + (size_t)GROUPS * N_ELEM * 2);

  permbuild_kernel<<<GROUPS * TRACE_BLOCKS, TPB, 0, stream>>>(Pg);
  compose_kernel<<<TRACE_BLOCKS, TPB, 0, stream>>>(Pg, perm);
  gather_kernel<<<N_ROWS / ROWS_PB, GTPB, 0, stream>>>(x, perm, out);
}

// Round 5
// 249.843 us; speedup vs baseline: 1.1022x; 1.0789x over previous
//
#include <hip/hip_runtime.h>

// Problem constants (x: (512, 9, 84, 84) f32)
#define N_ELEM   7056        // 84*84
#define DIM      84
#define M_STEPS  14111       // 2*N_ELEM - 1
#define N_ROWS   4608        // 512*9
#define NCHUNK   384
#define KSTEPS   37          // 384*37 = 14208 >= 14111 (tail chunks empty -> identity)
#define WINW     208         // window: (K-1)+2*84+1 = 205, padded to 208
#define TPB      256
#define NJV      1764        // N_ELEM / 4

#define TRACE_BLOCKS 28      // 28 * 252 = 7056
#define GROUPS   16          // chunk groups for parallel partial maps
#define CPG      (NCHUNK / GROUPS)   // 24 chunks per group

#define GTPB     512         // gather block size (8 waves; LDS caps at 4 blocks/CU = 32 waves)
#define ROWS_PB  2           // rows per gather block -> grid 2304 (9 blocks/CU demand)
#define GK       4           // ceil(NJV / GTPB)

// ---- JAX threefry2x32 block cipher (20 rounds), bit-exact port ----
__device__ __forceinline__ void threefry2x32(unsigned k0, unsigned k1,
                                             unsigned x0, unsigned x1,
                                             unsigned &o0, unsigned &o1) {
  const unsigned ks0 = k0, ks1 = k1, ks2 = k0 ^ k1 ^ 0x1BD11BDAu;
  x0 += ks0; x1 += ks1;
#define ROTL(x, r) (((x) << (r)) | ((x) >> (32 - (r))))
#define RND(r) { x0 += x1; x1 = ROTL(x1, r); x1 ^= x0; }
  RND(13) RND(15) RND(26) RND(6)
  x0 += ks1; x1 += ks2 + 1u;
  RND(17) RND(29) RND(16) RND(24)
  x0 += ks2; x1 += ks0 + 2u;
  RND(13) RND(15) RND(26) RND(6)
  x0 += ks0; x1 += ks1 + 3u;
  RND(17) RND(29) RND(16) RND(24)
  x0 += ks1; x1 += ks2 + 4u;
  RND(13) RND(15) RND(26) RND(6)
  x0 += ks2; x1 += ks0 + 5u;
  o0 = x0; o1 = x1;
#undef RND
#undef ROTL
}

// jax.random.choice(key,5,p=[.55,.1125,.1125,.1125,.1125]) — searchsorted on f32
// cumsum (sequential f32 cumsum verified exact-arithmetic: q4 == 1.0f exactly).
__device__ __forceinline__ int r_from_bits(unsigned bits) {
  const float p8 = 0.1125f;
  const float q0 = 0.55f;
  const float q1 = q0 + p8;
  const float q2 = q1 + p8;
  const float q3 = q2 + p8;
  const float q4 = q3 + p8;
  float u  = __uint_as_float((bits >> 9) | 0x3F800000u) - 1.0f; // [0,1)
  float rv = q4 * (1.0f - u);
  return (int)(q0 < rv) + (int)(q1 < rv) + (int)(q2 < rv) + (int)(q3 < rv);
}

// Window bounds for chunk c: steps t in [t0,t1); touched positions are within
// [imin-DIM, imax+DIM] clamped to [0, N_ELEM-1], where i(t) = |t - (N_ELEM-1)|.
__device__ __forceinline__ void chunk_bounds(int c, int &t0, int &t1, int &lo, int &hi) {
  t0 = c * KSTEPS; if (t0 > M_STEPS) t0 = M_STEPS;
  t1 = t0 + KSTEPS; if (t1 > M_STEPS) t1 = M_STEPS;
  int a0 = t0 - (N_ELEM - 1);       if (a0 < 0) a0 = -a0;
  int a1 = (t1 - 1) - (N_ELEM - 1); if (a1 < 0) a1 = -a1;
  int imax = a0 > a1 ? a0 : a1;
  int imin;
  if (t0 <= N_ELEM - 1 && t1 - 1 >= N_ELEM - 1) imin = 0;
  else imin = a0 < a1 ? a0 : a1;
  lo = imin - DIM; if (lo < 0) lo = 0;
  hi = imax + DIM; if (hi > N_ELEM - 1) hi = N_ELEM - 1;
}

// Kernel 1 (merged chunk+trace): each block rebuilds its group's 24 chunk
// windows LOCALLY in LDS (lanes 0..23 run the 24 independent 37-step serial
// swap chains in parallel), then traces 252 indices through the group's
// chunks (c descending). Output P_g[y] as ushort.
__global__ __launch_bounds__(TPB) void permbuild_kernel(unsigned short* __restrict__ Pg) {
  __shared__ __align__(16) unsigned short w[CPG * WINW];   // 24*208*2 = 9984 B
  __shared__ unsigned char rs[CPG * KSTEPS];               // 888 B
  const int tid = threadIdx.x;
  const int g  = blockIdx.x / TRACE_BLOCKS;
  const int sb = blockIdx.x % TRACE_BLOCKS;

  // identity-init all 24 windows
  for (int idx = tid; idx < CPG * WINW; idx += TPB) {
    int c = idx / WINW;
    int j = idx - c * WINW;
    int t0, t1, lo, hi; chunk_bounds(g * CPG + c, t0, t1, lo, hi);
    w[idx] = (unsigned short)(lo + j);                     // pad entries unused
  }
  // all draws for the group's 24 chunks, computed in parallel
  for (int q = tid; q < CPG * KSTEPS; q += TPB) {
    int c = q / KSTEPS;
    int k = q - c * KSTEPS;
    int t = (g * CPG + c) * KSTEPS + k;
    unsigned y0, y1;
    threefry2x32(0u, 42u, 0u, (unsigned)t, y0, y1);
    rs[q] = (unsigned char)r_from_bits(y0 ^ y1);
  }
  __syncthreads();

  // 24 parallel serial swap chains (lane c owns chunk g*CPG+c)
  if (tid < CPG) {
    const int c = tid;
    int t0, t1, lo, hi; chunk_bounds(g * CPG + c, t0, t1, lo, hi);
    const int nt = t1 - t0;
    unsigned short* wc = &w[c * WINW];
    const unsigned char* rc = &rs[c * KSTEPS];
    for (int k = 0; k < nt; ++k) {
      int t = t0 + k;
      int i = t - (N_ELEM - 1); if (i < 0) i = -i;
      int r = rc[k];
      int off = (r == 1) ? 1 : (r == 2) ? -1 : (r == 3) ? DIM : (r == 4) ? -DIM : 0;
      int idx = i + off;
      bool doit = (r != 0) && (idx > 0) && (idx < N_ELEM);
      int je = doit ? idx : i;              // branchless self-swap when !doit
      unsigned short a = wc[i  - lo];
      unsigned short b = wc[je - lo];
      wc[i  - lo] = b;
      wc[je - lo] = a;
    }
  }
  __syncthreads();

  // trace 252 indices through chunks c = CPG-1 .. 0 of this group
  if (tid < 252) {
    int y = sb * 252 + tid;
    for (int c = CPG - 1; c >= 0; --c) {
      int t0, t1, lo, hi; chunk_bounds(g * CPG + c, t0, t1, lo, hi);
      unsigned e = (unsigned)(y - lo);
      if (e <= (unsigned)(hi - lo)) y = (int)w[c * WINW + e];
    }
    Pg[g * N_ELEM + sb * 252 + tid] = (unsigned short)y;
  }
}

// Kernel 2: compose the 16 partial maps: perm[j] = P_0[P_1[...P_15[j]]].
// (P_15 applied first = chunks 383..360, matching the original c=383..0 walk.)
__global__ __launch_bounds__(TPB) void compose_kernel(const unsigned short* __restrict__ Pg,
                                                      int* __restrict__ permG) {
  const int tid = threadIdx.x;
  if (tid >= 252) return;
  const int j = blockIdx.x * 252 + tid;
  int y = j;
#pragma unroll
  for (int g = GROUPS - 1; g >= 0; --g) y = (int)Pg[g * N_ELEM + y];
  permG[j] = y;
}

// Kernel 3: per-row LDS-staged gather, 2 rows per block, TPB=512.
// R1 structure (direct global->LDS, no register prefetch — prefetch buf was
// spilling to scratch and DOUBLING write traffic in rounds 3-4).
// __launch_bounds__(512,4): VGPR cap 128 (needs ~40, no spill); runtime
// occupancy LDS-capped at 4 blocks/CU * 8 waves = 32 waves (100%).
__global__ __launch_bounds__(GTPB, 4) void gather_kernel(const float* __restrict__ x,
                                                         const int* __restrict__ perm,
                                                         float* __restrict__ out) {
  __shared__ __align__(16) float row[N_ELEM];             // 28224 B
  const int tid = threadIdx.x;
  const int r0 = blockIdx.x * ROWS_PB;
  float4* row4 = (float4*)row;

  // perm fragment in registers (reused for both rows)
  int4 p[GK];
  const int4* p4 = (const int4*)perm;
#pragma unroll
  for (int k = 0; k < GK; ++k) {
    int v = tid + k * GTPB;
    if (v < NJV) p[k] = p4[v];
  }

  for (int rr = 0; rr < ROWS_PB; ++rr) {
    const int r = r0 + rr;
    // direct global -> LDS (compiler pipelines the load/store pairs)
    const float4* xr4 = (const float4*)(x + (size_t)r * N_ELEM);
#pragma unroll
    for (int k = 0; k < GK; ++k) {
      int v = tid + k * GTPB;
      if (v < NJV) row4[v] = xr4[v];
    }
    __syncthreads();

    // gather from LDS, coalesced float4 store
    float4* or4 = (float4*)(out + (size_t)r * N_ELEM);
#pragma unroll
    for (int k = 0; k < GK; ++k) {
      int v = tid + k * GTPB;
      if (v < NJV) {
        int4 pp = p[k];
        float4 o;
        o.x = row[pp.x]; o.y = row[pp.y]; o.z = row[pp.z]; o.w = row[pp.w];
        or4[v] = o;
      }
    }
    __syncthreads();   // LDS reads done before next row's write
  }
}

extern "C" void kernel_launch(void* const* d_in, const int* in_sizes, int n_in,
                              void* d_out, int out_size, void* d_ws, size_t ws_size,
                              hipStream_t stream) {
  const float* x = (const float*)d_in[0];
  float* out = (float*)d_out;

  // ws layout: Pg 225792 B | perm 28224 B
  unsigned short* Pg = (unsigned short*)d_ws;
  int* perm = (int*)((char*)d_ws + (size_t)GROUPS * N_ELEM * 2);

  permbuild_kernel<<<GROUPS * TRACE_BLOCKS, TPB, 0, stream>>>(Pg);
  compose_kernel<<<TRACE_BLOCKS, TPB, 0, stream>>>(Pg, perm);
  gather_kernel<<<N_ROWS / ROWS_PB, GTPB, 0, stream>>>(x, perm, out);
}